// Round 1
// baseline (205.746 us; speedup 1.0000x reference)
//
#include <hip/hip_runtime.h>

#define NROWS 4096
#define DIM   1024

using f32x4 = __attribute__((ext_vector_type(4))) float;
using bfrag = __attribute__((ext_vector_type(8))) short;

__device__ __forceinline__ unsigned short f2bf(float f) {
  unsigned u = __float_as_uint(f);
  u += 0x7fffu + ((u >> 16) & 1u);
  return (unsigned short)(u >> 16);
}
__device__ __forceinline__ float bf2f(unsigned short b) {
  return __uint_as_float(((unsigned)b) << 16);
}
__device__ __forceinline__ unsigned long long shflx64(unsigned long long v, int m) {
  int lo = __shfl_xor((int)(unsigned)(v & 0xffffffffull), m);
  int hi = __shfl_xor((int)(unsigned)(v >> 32), m);
  return ((unsigned long long)(unsigned)hi << 32) | (unsigned)lo;
}

__global__ void init_kernel(int* maxS, int* maxD, unsigned long long* minS,
                            unsigned long long* minD, float* out) {
  int i = blockIdx.x * 256 + threadIdx.x;
  if (i < NROWS) { maxS[i] = 0; maxD[i] = 0; minS[i] = ~0ull; minD[i] = ~0ull; }
  if (i == 0) out[0] = 0.f;
}

// fp32 -> bf16 (RNE) conversion + row squared-norms from the bf16-rounded values
__global__ void prep_kernel(const float* __restrict__ X, unsigned short* __restrict__ Xb,
                            float* __restrict__ sqv) {
  int row = blockIdx.x, t = threadIdx.x;  // 256 threads, 4 floats each
  float4 v = reinterpret_cast<const float4*>(X + (size_t)row * DIM)[t];
  unsigned short b0 = f2bf(v.x), b1 = f2bf(v.y), b2 = f2bf(v.z), b3 = f2bf(v.w);
  float f0 = bf2f(b0), f1 = bf2f(b1), f2 = bf2f(b2), f3 = bf2f(b3);
  float s = f0 * f0 + f1 * f1 + f2 * f2 + f3 * f3;
  reinterpret_cast<ushort4*>(Xb + (size_t)row * DIM)[t] = make_ushort4(b0, b1, b2, b3);
  for (int m = 32; m; m >>= 1) s += __shfl_xor(s, m);
  __shared__ float ws4[4];
  if ((t & 63) == 0) ws4[t >> 6] = s;
  __syncthreads();
  if (t == 0) sqv[row] = (ws4[0] + ws4[1]) + (ws4[2] + ws4[3]);
}

// 128x128 bf16-MFMA Gram tile (triangular grid, symmetric) + fused masked reductions
__global__ __launch_bounds__(256) void gram_kernel(
    const unsigned short* __restrict__ Xb, const float* __restrict__ sqv,
    const int* __restrict__ tg, const int* __restrict__ fl,
    int* maxS, int* maxD, unsigned long long* minS, unsigned long long* minD) {
  __shared__ __attribute__((aligned(16))) char smem[128 * 133 * 4];  // As/Bs then Ds
  __shared__ float srow[128], scol[128];
  __shared__ int rtg[128], rfl[128], ctg[128], cfl[128];

  // triangular decode: tiles with tm <= tn (32x32 tile grid, 528 blocks)
  int tm = 0, g = blockIdx.x, rem = 32;
  while (g >= rem) { g -= rem; rem--; tm++; }
  int tn = tm + g;
  const int row0 = tm * 128, col0 = tn * 128;
  const int tid = threadIdx.x;
  const int wave = tid >> 6, lane = tid & 63;

  if (tid < 128) {
    srow[tid] = sqv[row0 + tid]; rtg[tid] = tg[row0 + tid]; rfl[tid] = fl[row0 + tid];
  } else {
    int c = tid - 128;
    scol[c] = sqv[col0 + c]; ctg[c] = tg[col0 + c]; cfl[c] = fl[col0 + c];
  }

  unsigned short (*As)[64] = (unsigned short (*)[64])smem;             // 16 KiB
  unsigned short (*Bs)[64] = (unsigned short (*)[64])(smem + 16384);   // 16 KiB
  float (*Ds)[133] = (float (*)[133])smem;                             // aliased after GEMM

  f32x4 acc[4][4] = {};
  const int wr = (wave >> 1) * 64, wc = (wave & 1) * 64;

  for (int ks = 0; ks < DIM; ks += 64) {
    __syncthreads();  // previous tile fully consumed
    // stage A and B tiles (128x64 bf16 each) via global_load_lds, 16B/lane
#pragma unroll
    for (int q = 0; q < 4; ++q) {
      int baseA = (wave * 4 + q) * 1024;            // byte offset inside tile
      int elt = (baseA >> 1) + lane * 8;            // element offset of lane's 16B
      int r = elt >> 6, k = elt & 63;
      const unsigned short* srcA = Xb + (size_t)(row0 + r) * DIM + ks + k;
      __builtin_amdgcn_global_load_lds(
          (const __attribute__((address_space(1))) void*)srcA,
          (__attribute__((address_space(3))) void*)(smem + baseA), 16, 0, 0);
      const unsigned short* srcB = Xb + (size_t)(col0 + r) * DIM + ks + k;
      __builtin_amdgcn_global_load_lds(
          (const __attribute__((address_space(1))) void*)srcB,
          (__attribute__((address_space(3))) void*)(smem + 16384 + baseA), 16, 0, 0);
    }
    __syncthreads();  // staging complete
#pragma unroll
    for (int kk = 0; kk < 2; ++kk) {
      bfrag a[4], b[4];
      int krow = kk * 32 + (lane >> 4) * 8;  // same k-map for A and B -> Gram safe
#pragma unroll
      for (int m = 0; m < 4; ++m)
        a[m] = *(const bfrag*)&As[wr + m * 16 + (lane & 15)][krow];
#pragma unroll
      for (int n = 0; n < 4; ++n)
        b[n] = *(const bfrag*)&Bs[wc + n * 16 + (lane & 15)][krow];
#pragma unroll
      for (int m = 0; m < 4; ++m)
#pragma unroll
        for (int n = 0; n < 4; ++n)
          acc[m][n] = __builtin_amdgcn_mfma_f32_16x16x32_bf16(a[m], b[n], acc[m][n], 0, 0, 0);
    }
  }
  __syncthreads();  // all LDS reads done before aliasing Ds over As/Bs

  // epilogue: dist = sqrt(clamp(|xi|^2 + |xj|^2 - 2<xi,xj>, 1e-12)) into LDS
#pragma unroll
  for (int m = 0; m < 4; ++m)
#pragma unroll
    for (int n = 0; n < 4; ++n)
#pragma unroll
      for (int r = 0; r < 4; ++r) {
        int lr = wr + m * 16 + (lane >> 4) * 4 + r;  // C/D layout (m89-verified)
        int lc = wc + n * 16 + (lane & 15);
        float dsq = srow[lr] + scol[lc] - 2.0f * acc[m][n][r];
        Ds[lr][lc] = sqrtf(fmaxf(dsq, 1e-12f));
      }
  __syncthreads();

  // pass A: reduce rows (row0+r) over cols (col0+c)
  {
    int r = tid >> 1, h = tid & 1;
    int ti = rtg[r], fi = rfl[r];
    float mxS = -1.f, mxD = -1.f;
    unsigned long long mnS = ~0ull, mnD = ~0ull;
    for (int c0 = 0; c0 < 64; ++c0) {
      int c = h * 64 + c0;
      float d = Ds[r][c];
      unsigned long long pk =
          ((unsigned long long)__float_as_uint(d) << 32) | (unsigned)(col0 + c);
      bool sid = (ctg[c] == ti), sfl = (cfl[c] == fi);
      if (sid) { if (sfl) mxS = fmaxf(mxS, d); else mxD = fmaxf(mxD, d); }
      else     { if (sfl) { if (pk < mnS) mnS = pk; } else { if (pk < mnD) mnD = pk; } }
    }
    mxS = fmaxf(mxS, __shfl_xor(mxS, 1));
    mxD = fmaxf(mxD, __shfl_xor(mxD, 1));
    unsigned long long o = shflx64(mnS, 1); if (o < mnS) mnS = o;
    o = shflx64(mnD, 1); if (o < mnD) mnD = o;
    if (h == 0) {
      atomicMax(&maxS[row0 + r], __float_as_int(mxS));
      atomicMax(&maxD[row0 + r], __float_as_int(mxD));
      atomicMin(&minS[row0 + r], mnS);
      atomicMin(&minD[row0 + r], mnD);
    }
  }
  // pass B (transposed roles): reduce rows (col0+cc) over cols (row0+rr).
  // Idempotent on diagonal tiles (max/min of identical values).
  {
    int cc = tid >> 1, h = tid & 1;
    int tj = ctg[cc], fj = cfl[cc];
    float mxS = -1.f, mxD = -1.f;
    unsigned long long mnS = ~0ull, mnD = ~0ull;
    for (int r0 = 0; r0 < 64; ++r0) {
      int rr = h * 64 + r0;
      float d = Ds[rr][cc];
      unsigned long long pk =
          ((unsigned long long)__float_as_uint(d) << 32) | (unsigned)(row0 + rr);
      bool sid = (rtg[rr] == tj), sfl = (rfl[rr] == fj);
      if (sid) { if (sfl) mxS = fmaxf(mxS, d); else mxD = fmaxf(mxD, d); }
      else     { if (sfl) { if (pk < mnS) mnS = pk; } else { if (pk < mnD) mnD = pk; } }
    }
    mxS = fmaxf(mxS, __shfl_xor(mxS, 1));
    mxD = fmaxf(mxD, __shfl_xor(mxD, 1));
    unsigned long long o = shflx64(mnS, 1); if (o < mnS) mnS = o;
    o = shflx64(mnD, 1); if (o < mnD) mnD = o;
    if (h == 0) {
      atomicMax(&maxS[col0 + cc], __float_as_int(mxS));
      atomicMax(&maxD[col0 + cc], __float_as_int(mxD));
      atomicMin(&minS[col0 + cc], mnS);
      atomicMin(&minD[col0 + cc], mnD);
    }
  }
}

// per-row: recompute dist[same_min_idx, dif_min_idx], accumulate the three relu means
__global__ void finish_kernel(const unsigned short* __restrict__ Xb,
                              const float* __restrict__ sqv,
                              const int* __restrict__ maxS, const int* __restrict__ maxD,
                              const unsigned long long* __restrict__ minS,
                              const unsigned long long* __restrict__ minD, float* out) {
  int row = blockIdx.x * 4 + (threadIdx.x >> 6);
  int lane = threadIdx.x & 63;
  unsigned long long pS = minS[row], pD = minD[row];
  int ia = (int)(pS & 0xffffffffull);  // same_min_idx (row of gather)
  int ib = (int)(pD & 0xffffffffull);  // dif_min_idx  (col of gather)
  const ushort4* pa = (const ushort4*)(Xb + (size_t)ia * DIM);
  const ushort4* pb = (const ushort4*)(Xb + (size_t)ib * DIM);
  float s = 0.f;
#pragma unroll
  for (int q = 0; q < 4; ++q) {
    ushort4 a = pa[lane + q * 64], b = pb[lane + q * 64];
    s += bf2f(a.x) * bf2f(b.x) + bf2f(a.y) * bf2f(b.y) +
         bf2f(a.z) * bf2f(b.z) + bf2f(a.w) * bf2f(b.w);
  }
  for (int m = 32; m; m >>= 1) s += __shfl_xor(s, m);
  if (lane == 0) {
    float dneg = sqrtf(fmaxf(sqv[ia] + sqv[ib] - 2.f * s, 1e-12f));
    float mS = __int_as_float(maxS[row]);
    float mD = __int_as_float(maxD[row]);
    float mnSv = __uint_as_float((unsigned)(pS >> 32));
    float mnDv = __uint_as_float((unsigned)(pD >> 32));
    float t = fmaxf(mS - mnSv + 0.8f, 0.f) + fmaxf(mD - mnDv + 0.5f, 0.f) +
              fmaxf(mS - dneg + 0.3f, 0.f);
    atomicAdd(out, t * (1.0f / 4096.0f));
  }
}

extern "C" void kernel_launch(void* const* d_in, const int* in_sizes, int n_in,
                              void* d_out, int out_size, void* d_ws, size_t ws_size,
                              hipStream_t stream) {
  const float* X = (const float*)d_in[0];
  const int* tg  = (const int*)d_in[1];
  const int* fl  = (const int*)d_in[2];
  float* out = (float*)d_out;

  // workspace layout (8.5 MB total)
  char* w = (char*)d_ws;
  unsigned short* Xb = (unsigned short*)(w);                    // 8,388,608 B
  float* sqv = (float*)(w + 8388608);                           //    16,384 B
  int* maxS  = (int*)(w + 8404992);                             //    16,384 B
  int* maxD  = (int*)(w + 8421376);                             //    16,384 B
  unsigned long long* minS = (unsigned long long*)(w + 8437760);//    32,768 B
  unsigned long long* minD = (unsigned long long*)(w + 8470528);//    32,768 B

  init_kernel<<<16, 256, 0, stream>>>(maxS, maxD, minS, minD, out);
  prep_kernel<<<NROWS, 256, 0, stream>>>(X, Xb, sqv);
  gram_kernel<<<528, 256, 0, stream>>>(Xb, sqv, tg, fl, maxS, maxD, minS, minD);
  finish_kernel<<<NROWS / 4, 256, 0, stream>>>(Xb, sqv, maxS, maxD, minS, minD, out);
}

// Round 2
// 153.702 us; speedup vs baseline: 1.3386x; 1.3386x over previous
//
#include <hip/hip_runtime.h>

#define NROWS 4096
#define DIM   1024

using f32x4 = __attribute__((ext_vector_type(4))) float;
using bfrag = __attribute__((ext_vector_type(8))) short;

__device__ __forceinline__ unsigned short f2bf(float f) {
  unsigned u = __float_as_uint(f);
  u += 0x7fffu + ((u >> 16) & 1u);
  return (unsigned short)(u >> 16);
}
__device__ __forceinline__ float bf2f(unsigned short b) {
  return __uint_as_float(((unsigned)b) << 16);
}
__device__ __forceinline__ unsigned long long shflx64(unsigned long long v, int m) {
  int lo = __shfl_xor((int)(unsigned)(v & 0xffffffffull), m);
  int hi = __shfl_xor((int)(unsigned)(v >> 32), m);
  return ((unsigned long long)(unsigned)hi << 32) | (unsigned)lo;
}

__global__ void init_kernel(int* maxS, int* maxD, unsigned long long* minS,
                            unsigned long long* minD, float* out) {
  int i = blockIdx.x * 256 + threadIdx.x;
  if (i < NROWS) { maxS[i] = 0; maxD[i] = 0; minS[i] = ~0ull; minD[i] = ~0ull; }
  if (i == 0) out[0] = 0.f;
}

// fp32 -> bf16 (RNE) conversion + row squared-norms from the bf16-rounded values
__global__ void prep_kernel(const float* __restrict__ X, unsigned short* __restrict__ Xb,
                            float* __restrict__ sqv) {
  int row = blockIdx.x, t = threadIdx.x;  // 256 threads, 4 floats each
  float4 v = reinterpret_cast<const float4*>(X + (size_t)row * DIM)[t];
  unsigned short b0 = f2bf(v.x), b1 = f2bf(v.y), b2 = f2bf(v.z), b3 = f2bf(v.w);
  float f0 = bf2f(b0), f1 = bf2f(b1), f2 = bf2f(b2), f3 = bf2f(b3);
  float s = f0 * f0 + f1 * f1 + f2 * f2 + f3 * f3;
  reinterpret_cast<ushort4*>(Xb + (size_t)row * DIM)[t] = make_ushort4(b0, b1, b2, b3);
  for (int m = 32; m; m >>= 1) s += __shfl_xor(s, m);
  __shared__ float ws4[4];
  if ((t & 63) == 0) ws4[t >> 6] = s;
  __syncthreads();
  if (t == 0) sqv[row] = (ws4[0] + ws4[1]) + (ws4[2] + ws4[3]);
}

// 128x128 bf16-MFMA Gram tile (triangular grid, symmetric) + fused masked reductions.
// LDS k-slot XOR swizzle (T2, rule-21 form): LDS[r][slot] holds global k-slot
// slot^(r&7); staged via inverse-swizzled GLOBAL source (dest stays linear for
// global_load_lds), fragment reads use slot s^(lane&7). Bit-exact involution.
__global__ __launch_bounds__(256) void gram_kernel(
    const unsigned short* __restrict__ Xb, const float* __restrict__ sqv,
    const int* __restrict__ tg, const int* __restrict__ fl,
    int* maxS, int* maxD, unsigned long long* minS, unsigned long long* minD) {
  __shared__ __attribute__((aligned(16))) char smem[128 * 133 * 4];  // As/Bs then Ds
  __shared__ float srow[128], scol[128];
  __shared__ int rtg[128], rfl[128], ctg[128], cfl[128];

  // triangular decode: tiles with tm <= tn (32x32 tile grid, 528 blocks)
  int tm = 0, g = blockIdx.x, rem = 32;
  while (g >= rem) { g -= rem; rem--; tm++; }
  int tn = tm + g;
  const int row0 = tm * 128, col0 = tn * 128;
  const int tid = threadIdx.x;
  const int wave = tid >> 6, lane = tid & 63;

  if (tid < 128) {
    srow[tid] = sqv[row0 + tid]; rtg[tid] = tg[row0 + tid]; rfl[tid] = fl[row0 + tid];
  } else {
    int c = tid - 128;
    scol[c] = sqv[col0 + c]; ctg[c] = tg[col0 + c]; cfl[c] = fl[col0 + c];
  }

  unsigned short (*As)[64] = (unsigned short (*)[64])smem;             // 16 KiB
  unsigned short (*Bs)[64] = (unsigned short (*)[64])(smem + 16384);   // 16 KiB
  float (*Ds)[133] = (float (*)[133])smem;                             // aliased after GEMM

  f32x4 acc[4][4] = {};
  const int wr = (wave >> 1) * 64, wc = (wave & 1) * 64;
  // per-lane inverse swizzle for staging: lane's 16B lands at row r = base8+(lane>>3),
  // slot = lane&7; source must be global k-slot (slot ^ (r&7)) = (lane&7)^(lane>>3).
  const int ksrc = ((lane & 7) ^ (lane >> 3)) * 8;  // element offset within 64-wide k

  for (int ks = 0; ks < DIM; ks += 64) {
    __syncthreads();  // previous tile fully consumed
#pragma unroll
    for (int q = 0; q < 4; ++q) {
      int base = (wave * 4 + q) * 1024;             // byte offset inside tile (8 rows)
      int r = (base >> 7) + (lane >> 3);            // local row this lane fills
      const unsigned short* srcA = Xb + (size_t)(row0 + r) * DIM + ks + ksrc;
      __builtin_amdgcn_global_load_lds(
          (const __attribute__((address_space(1))) void*)srcA,
          (__attribute__((address_space(3))) void*)(smem + base), 16, 0, 0);
      const unsigned short* srcB = Xb + (size_t)(col0 + r) * DIM + ks + ksrc;
      __builtin_amdgcn_global_load_lds(
          (const __attribute__((address_space(1))) void*)srcB,
          (__attribute__((address_space(3))) void*)(smem + 16384 + base), 16, 0, 0);
    }
    __syncthreads();  // staging complete
#pragma unroll
    for (int kk = 0; kk < 2; ++kk) {
      bfrag a[4], b[4];
      // want k-slot s = kk*4 + (lane>>4) of row rA; it lives at LDS slot s^(rA&7),
      // and rA&7 == lane&7 for all m/n (wr/wc, m*16 are multiples of 8).
      int kel = ((kk * 4 + (lane >> 4)) ^ (lane & 7)) * 8;
#pragma unroll
      for (int m = 0; m < 4; ++m)
        a[m] = *(const bfrag*)&As[wr + m * 16 + (lane & 15)][kel];
#pragma unroll
      for (int n = 0; n < 4; ++n)
        b[n] = *(const bfrag*)&Bs[wc + n * 16 + (lane & 15)][kel];
#pragma unroll
      for (int m = 0; m < 4; ++m)
#pragma unroll
        for (int n = 0; n < 4; ++n)
          acc[m][n] = __builtin_amdgcn_mfma_f32_16x16x32_bf16(a[m], b[n], acc[m][n], 0, 0, 0);
    }
  }
  __syncthreads();  // all LDS reads done before aliasing Ds over As/Bs

  // epilogue: dist = sqrt(clamp(|xi|^2 + |xj|^2 - 2<xi,xj>, 1e-12)) into LDS
#pragma unroll
  for (int m = 0; m < 4; ++m)
#pragma unroll
    for (int n = 0; n < 4; ++n)
#pragma unroll
      for (int r = 0; r < 4; ++r) {
        int lr = wr + m * 16 + (lane >> 4) * 4 + r;  // C/D layout (m89-verified)
        int lc = wc + n * 16 + (lane & 15);
        float dsq = srow[lr] + scol[lc] - 2.0f * acc[m][n][r];
        Ds[lr][lc] = sqrtf(fmaxf(dsq, 1e-12f));
      }
  __syncthreads();

  // pass A: reduce rows (row0+r) over cols (col0+c)
  {
    int r = tid >> 1, h = tid & 1;
    int ti = rtg[r], fi = rfl[r];
    float mxS = -1.f, mxD = -1.f;
    unsigned long long mnS = ~0ull, mnD = ~0ull;
    for (int c0 = 0; c0 < 64; ++c0) {
      int c = h * 64 + c0;
      float d = Ds[r][c];
      unsigned long long pk =
          ((unsigned long long)__float_as_uint(d) << 32) | (unsigned)(col0 + c);
      bool sid = (ctg[c] == ti), sfl = (cfl[c] == fi);
      if (sid) { if (sfl) mxS = fmaxf(mxS, d); else mxD = fmaxf(mxD, d); }
      else     { if (sfl) { if (pk < mnS) mnS = pk; } else { if (pk < mnD) mnD = pk; } }
    }
    mxS = fmaxf(mxS, __shfl_xor(mxS, 1));
    mxD = fmaxf(mxD, __shfl_xor(mxD, 1));
    unsigned long long o = shflx64(mnS, 1); if (o < mnS) mnS = o;
    o = shflx64(mnD, 1); if (o < mnD) mnD = o;
    if (h == 0) {
      atomicMax(&maxS[row0 + r], __float_as_int(mxS));
      atomicMax(&maxD[row0 + r], __float_as_int(mxD));
      atomicMin(&minS[row0 + r], mnS);
      atomicMin(&minD[row0 + r], mnD);
    }
  }
  // pass B (transposed roles): reduce rows (col0+cc) over cols (row0+rr).
  // Idempotent on diagonal tiles (max/min of identical values).
  {
    int cc = tid >> 1, h = tid & 1;
    int tj = ctg[cc], fj = cfl[cc];
    float mxS = -1.f, mxD = -1.f;
    unsigned long long mnS = ~0ull, mnD = ~0ull;
    for (int r0 = 0; r0 < 64; ++r0) {
      int rr = h * 64 + r0;
      float d = Ds[rr][cc];
      unsigned long long pk =
          ((unsigned long long)__float_as_uint(d) << 32) | (unsigned)(row0 + rr);
      bool sid = (rtg[rr] == tj), sfl = (rfl[rr] == fj);
      if (sid) { if (sfl) mxS = fmaxf(mxS, d); else mxD = fmaxf(mxD, d); }
      else     { if (sfl) { if (pk < mnS) mnS = pk; } else { if (pk < mnD) mnD = pk; } }
    }
    mxS = fmaxf(mxS, __shfl_xor(mxS, 1));
    mxD = fmaxf(mxD, __shfl_xor(mxD, 1));
    unsigned long long o = shflx64(mnS, 1); if (o < mnS) mnS = o;
    o = shflx64(mnD, 1); if (o < mnD) mnD = o;
    if (h == 0) {
      atomicMax(&maxS[col0 + cc], __float_as_int(mxS));
      atomicMax(&maxD[col0 + cc], __float_as_int(mxD));
      atomicMin(&minS[col0 + cc], mnS);
      atomicMin(&minD[col0 + cc], mnD);
    }
  }
}

// per-row: recompute dist[same_min_idx, dif_min_idx], accumulate the three relu
// means. 128 blocks x 32 rows; ONE same-address atomicAdd per block (G12).
__global__ void finish_kernel(const unsigned short* __restrict__ Xb,
                              const float* __restrict__ sqv,
                              const int* __restrict__ maxS, const int* __restrict__ maxD,
                              const unsigned long long* __restrict__ minS,
                              const unsigned long long* __restrict__ minD, float* out) {
  int wave = threadIdx.x >> 6, lane = threadIdx.x & 63;
  float part = 0.f;
  for (int rr = 0; rr < 8; ++rr) {
    int row = blockIdx.x * 32 + wave * 8 + rr;
    unsigned long long pS = minS[row], pD = minD[row];
    int ia = (int)(pS & 0xffffffffull);  // same_min_idx (row of gather)
    int ib = (int)(pD & 0xffffffffull);  // dif_min_idx  (col of gather)
    const ushort4* pa = (const ushort4*)(Xb + (size_t)ia * DIM);
    const ushort4* pb = (const ushort4*)(Xb + (size_t)ib * DIM);
    float s = 0.f;
#pragma unroll
    for (int q = 0; q < 4; ++q) {
      ushort4 a = pa[lane + q * 64], b = pb[lane + q * 64];
      s += bf2f(a.x) * bf2f(b.x) + bf2f(a.y) * bf2f(b.y) +
           bf2f(a.z) * bf2f(b.z) + bf2f(a.w) * bf2f(b.w);
    }
    for (int m = 32; m; m >>= 1) s += __shfl_xor(s, m);
    if (lane == 0) {
      float dneg = sqrtf(fmaxf(sqv[ia] + sqv[ib] - 2.f * s, 1e-12f));
      float mS = __int_as_float(maxS[row]);
      float mD = __int_as_float(maxD[row]);
      float mnSv = __uint_as_float((unsigned)(pS >> 32));
      float mnDv = __uint_as_float((unsigned)(pD >> 32));
      part += fmaxf(mS - mnSv + 0.8f, 0.f) + fmaxf(mD - mnDv + 0.5f, 0.f) +
              fmaxf(mS - dneg + 0.3f, 0.f);
    }
  }
  __shared__ float wp[4];
  if (lane == 0) wp[wave] = part;
  __syncthreads();
  if (threadIdx.x == 0)
    atomicAdd(out, ((wp[0] + wp[1]) + (wp[2] + wp[3])) * (1.0f / 4096.0f));
}

extern "C" void kernel_launch(void* const* d_in, const int* in_sizes, int n_in,
                              void* d_out, int out_size, void* d_ws, size_t ws_size,
                              hipStream_t stream) {
  const float* X = (const float*)d_in[0];
  const int* tg  = (const int*)d_in[1];
  const int* fl  = (const int*)d_in[2];
  float* out = (float*)d_out;

  // workspace layout (8.5 MB total)
  char* w = (char*)d_ws;
  unsigned short* Xb = (unsigned short*)(w);                    // 8,388,608 B
  float* sqv = (float*)(w + 8388608);                           //    16,384 B
  int* maxS  = (int*)(w + 8404992);                             //    16,384 B
  int* maxD  = (int*)(w + 8421376);                             //    16,384 B
  unsigned long long* minS = (unsigned long long*)(w + 8437760);//    32,768 B
  unsigned long long* minD = (unsigned long long*)(w + 8470528);//    32,768 B

  init_kernel<<<16, 256, 0, stream>>>(maxS, maxD, minS, minD, out);
  prep_kernel<<<NROWS, 256, 0, stream>>>(X, Xb, sqv);
  gram_kernel<<<528, 256, 0, stream>>>(Xb, sqv, tg, fl, maxS, maxD, minS, minD);
  finish_kernel<<<128, 256, 0, stream>>>(Xb, sqv, maxS, maxD, minS, minD, out);
}